// Round 6
// baseline (72.883 us; speedup 1.0000x reference)
//
#include <hip/hip_runtime.h>

constexpr int Bn = 1024;
constexpr int Nn = 128;   // pred points per batch
constexpr int Mn = 128;   // gt points per batch

// R5/R6 sync: hierarchical completion ticket, zero cache-maintenance.
// Each block publishes 12 B of partials with agent-scope relaxed (sc1,
// write-through-to-IF$) stores, IF$-acked via `s_waitcnt vmcnt(0)` BEFORE
// its level-1 ticket RMW. 64 level-1 counters (16 blocks each, 64-B strided
// -> different IF$ banks, serialize in parallel). R6: the group-last block
// (ticket 15) pre-aggregates its group's 16 slots into one 64-B-strided
// level-2 slot, then takes the level-2 ticket; ticket 63 => all 64 group
// sums durable => finalizer (one wave) reads just 64 slots.
// Zero wbl2 / zero inv / zero threadfence anywhere.
__device__ unsigned long long g_ab[Bn];        // per-block packed (A, C)
__device__ unsigned int       g_m[Bn];         // per-block M bits
__device__ unsigned long long g2_ab[64 * 8];   // group sums, 64-B stride
__device__ unsigned int       g2_m[64 * 16];   // group sums, 64-B stride
__device__ unsigned int       g_c1[64 * 16];   // level-1 tickets, 64-B stride
__device__ unsigned int       g_c2 = 0;        // level-2 ticket
// g_c1/g_c2 zero-init at load; finalizer re-zeros each replay (it runs
// strictly after every RMW of the replay -> no race). Slot arrays need no
// reset (fully rewritten before read each replay).

// Phase A insight (unchanged): interp[m,t] = a + (t/10)*(b-a); dist quadratic
// in t -> evaluate only the clamped discrete vertex (convex: ee>0).
// Merged scan (R1): wave w owns segments/anchors [32w,32w+32); each lane
// holds 2 points in registers, so each wave-uniform broadcast LDS read is
// amortized over many point-evals.
// R6: segment record packed as two contiguous float4s -> inner loop does
// 2x ds_read_b128 instead of b128+b64+b64 (DS-instruction-bound scan).

__global__ __launch_bounds__(256) void dm_main(
    const float2* __restrict__ ini,    // [B,N]
    const float2* __restrict__ pred,   // [B,N]
    const float2* __restrict__ gt,     // [B,M]
    const float*  __restrict__ kpm,    // [B,M]
    float* __restrict__ out)           // [1]
{
    __shared__ float4 s_seg[2 * Mn];   // [2m]=(a.x,a.y,e.x,e.y) [2m+1]=(ee,nr,q.x,q.y)
    __shared__ float2 s_ini[Nn];
    __shared__ float2 s_pred[Nn];
    __shared__ float2 s_gt[Mn];
    __shared__ float4 s_cA[4][Nn];     // per-wave phase-A candidates: d, s, m
    __shared__ float2 s_cB[4][Mn];     // per-wave phase-B candidates: d, j
    __shared__ float  s_red[3][4];
    __shared__ bool   s_last;

    const int b   = blockIdx.x;
    const int tid = threadIdx.x;

    // kpm for the gt point this thread owns in the combine step (tid>=128);
    // issued at kernel start so latency hides under the scan.
    float kw = 0.f;
    if (tid >= Nn) kw = kpm[b*Mn + (tid - Nn)];

    // ---- stage, split across the two thread halves ----
    float2* s2 = reinterpret_cast<float2*>(s_seg);
    if (tid < Mn) {
        const float2 cur = gt[b*Mn + tid];
        const float2 prv = gt[b*Mn + ((tid + Mn - 1) & (Mn - 1))];
        const float ex = cur.x - prv.x, ey = cur.y - prv.y;
        const float ee = fmaxf(fmaf(ex, ex, ey*ey), 1e-30f);  // degenerate-seg guard
        const float nr = -10.0f * __builtin_amdgcn_rcpf(ee);
        s_seg[2*tid] = make_float4(prv.x, prv.y, ex, ey);
        s2[4*tid + 2] = make_float2(ee, nr);
        s_gt[tid]   = cur;
    } else {
        const int t = tid - Mn;
        const float2 iv = ini[b*Nn + t];
        s_ini[t]  = iv;
        s2[4*t + 3] = iv;              // q slot of the packed record
        s_pred[t] = pred[b*Nn + t];
    }
    __syncthreads();

    const int lane  = tid & 63;
    const int w     = tid >> 6;
    const int mbase = w * 32;          // this wave's segment/anchor range

    // two points per lane, held in registers
    const float2 p0 = s_ini[lane];
    const float2 p1 = s_ini[lane + 64];
    const float2 g0 = s_gt[lane];
    const float2 g1 = s_gt[lane + 64];

    float bd0 = 3.4e38f, bd1 = 3.4e38f;   // phase A best dist
    int   bm0 = 0,       bm1 = 0;          // best segment
    float bs0 = 0.f,     bs1 = 0.f;        // best s = t/10
    float cd0 = 3.4e38f, cd1 = 3.4e38f;   // phase B best dist
    int   cj0 = 0,       cj1 = 0;          // best anchor

    #pragma unroll 4
    for (int i = 0; i < 32; ++i) {
        const int m = mbase + i;                 // ascending -> first-min tie-break
        const float4 A = s_seg[2*m];             // wave-uniform broadcast b128
        const float4 E = s_seg[2*m + 1];         // ee, nr, q.x, q.y
        // ---- phase A, point 0 ----
        {
            const float fx = A.x - p0.x, fy = A.y - p0.y;
            const float fe = fmaf(fx, A.z, fy*A.w);
            const float ff = fmaf(fx, fx, fy*fy);
            const float tv = __builtin_amdgcn_fmed3f(rintf(fe * E.y), 0.f, 9.f);
            const float sp = tv * 0.1f;
            const float d  = fmaf(sp, fmaf(sp, E.x, fe + fe), ff);
            if (d < bd0) { bd0 = d; bm0 = m; bs0 = sp; }
        }
        // ---- phase A, point 1 ----
        {
            const float fx = A.x - p1.x, fy = A.y - p1.y;
            const float fe = fmaf(fx, A.z, fy*A.w);
            const float ff = fmaf(fx, fx, fy*fy);
            const float tv = __builtin_amdgcn_fmed3f(rintf(fe * E.y), 0.f, 9.f);
            const float sp = tv * 0.1f;
            const float d  = fmaf(sp, fmaf(sp, E.x, fe + fe), ff);
            if (d < bd1) { bd1 = d; bm1 = m; bs1 = sp; }
        }
        // ---- phase B, gt points 0/1 (anchor q = ini[m]) ----
        {
            const float dx = E.z - g0.x, dy = E.w - g0.y;
            const float d = fmaf(dx, dx, dy*dy);
            if (d < cd0) { cd0 = d; cj0 = m; }
        }
        {
            const float dx = E.z - g1.x, dy = E.w - g1.y;
            const float d = fmaf(dx, dx, dy*dy);
            if (d < cd1) { cd1 = d; cj1 = m; }
        }
    }

    // ---- publish per-wave candidates ----
    s_cA[w][lane]      = make_float4(bd0, bs0, __int_as_float(bm0), 0.f);
    s_cA[w][lane + 64] = make_float4(bd1, bs1, __int_as_float(bm1), 0.f);
    s_cB[w][lane]      = make_float2(cd0, __int_as_float(cj0));
    s_cB[w][lane + 64] = make_float2(cd1, __int_as_float(cj1));
    __syncthreads();

    // ---- cross-wave combine: waves cover ascending index ranges, so strict <
    //      in ascending wave order == lexicographic (d, index) first-min ----
    float sum_p2g = 0.f, sum_g2p = 0.f, sum_m = 0.f;
    if (tid < Nn) {
        const int n = tid;
        float best = 3.4e38f; float bs = 0.f; int bm = 0;
        #pragma unroll
        for (int w2 = 0; w2 < 4; ++w2) {
            const float4 c = s_cA[w2][n];
            if (c.x < best) { best = c.x; bs = c.y; bm = __float_as_int(c.z); }
        }
        const float4 A = s_seg[2*bm];
        const float ngx = fmaf(bs, A.z, A.x);
        const float ngy = fmaf(bs, A.w, A.y);
        const float2 pr = s_pred[n];
        sum_p2g = fabsf(pr.x - ngx) + fabsf(pr.y - ngy);
    } else {
        const int m = tid - Nn;
        float best = 3.4e38f; int nj = 0;
        #pragma unroll
        for (int w2 = 0; w2 < 4; ++w2) {
            const float2 c = s_cB[w2][m];
            if (c.x < best) { best = c.x; nj = __float_as_int(c.y); }
        }
        const float2 np_ = s_pred[nj];
        const float2 g   = s_gt[m];
        sum_g2p = kw * (fabsf(np_.x - g.x) + fabsf(np_.y - g.y));
        sum_m   = 2.0f * kw;
    }

    // ---- block reduction: 3 scalars over 256 threads ----
    #pragma unroll
    for (int off = 32; off > 0; off >>= 1) {
        sum_p2g += __shfl_down(sum_p2g, off);
        sum_g2p += __shfl_down(sum_g2p, off);
        sum_m   += __shfl_down(sum_m,   off);
    }
    const int wv = tid >> 6;
    if ((tid & 63) == 0) { s_red[0][wv] = sum_p2g; s_red[1][wv] = sum_g2p; s_red[2][wv] = sum_m; }
    __syncthreads();

    // ---- ticket (tid0): sc1 publish -> vmcnt(0) -> hierarchical RMWs ----
    if (tid == 0) {
        const float At = s_red[0][0] + s_red[0][1] + s_red[0][2] + s_red[0][3];
        const float Ct = s_red[1][0] + s_red[1][1] + s_red[1][2] + s_red[1][3];
        const float Mt = s_red[2][0] + s_red[2][1] + s_red[2][2] + s_red[2][3];
        const unsigned long long ab =
            ((unsigned long long)__float_as_uint(Ct) << 32) | __float_as_uint(At);
        __hip_atomic_store(&g_ab[b], ab, __ATOMIC_RELAXED, __HIP_MEMORY_SCOPE_AGENT);
        __hip_atomic_store(&g_m[b], __float_as_uint(Mt),
                           __ATOMIC_RELAXED, __HIP_MEMORY_SCOPE_AGENT);
        // sc1 store ack == durable at the coherent IF$; order before ticket
        asm volatile("s_waitcnt vmcnt(0)" ::: "memory");
        bool last = false;
        const unsigned t1 = __hip_atomic_fetch_add(&g_c1[b & ~15], 1u,
                                                   __ATOMIC_RELAXED,
                                                   __HIP_MEMORY_SCOPE_AGENT);
        if (t1 == 15u) {
            // group-last: all 16 slots of my group are durable -> pre-sum
            const int g = b >> 4;
            float gA = 0.f, gC = 0.f, gM = 0.f;
            #pragma unroll
            for (int k = 0; k < 16; ++k) {
                const unsigned long long v =
                    __hip_atomic_load(&g_ab[(g << 4) + k],
                                      __ATOMIC_RELAXED, __HIP_MEMORY_SCOPE_AGENT);
                const unsigned mm =
                    __hip_atomic_load(&g_m[(g << 4) + k],
                                      __ATOMIC_RELAXED, __HIP_MEMORY_SCOPE_AGENT);
                gA += __uint_as_float((unsigned)(v & 0xffffffffull));
                gC += __uint_as_float((unsigned)(v >> 32));
                gM += __uint_as_float(mm);
            }
            const unsigned long long gab =
                ((unsigned long long)__float_as_uint(gC) << 32) | __float_as_uint(gA);
            __hip_atomic_store(&g2_ab[g << 3], gab,
                               __ATOMIC_RELAXED, __HIP_MEMORY_SCOPE_AGENT);
            __hip_atomic_store(&g2_m[g << 4], __float_as_uint(gM),
                               __ATOMIC_RELAXED, __HIP_MEMORY_SCOPE_AGENT);
            asm volatile("s_waitcnt vmcnt(0)" ::: "memory");
            const unsigned t2 = __hip_atomic_fetch_add(&g_c2, 1u,
                                                       __ATOMIC_RELAXED,
                                                       __HIP_MEMORY_SCOPE_AGENT);
            last = (t2 == 63u);   // all 64 group sums durable
        }
        s_last = last;
    }
    __syncthreads();
    if (!s_last) return;

    // ---- last-block finalize: reset tickets, reduce the 64 group slots ----
    if (tid < 64) {
        __hip_atomic_store(&g_c1[tid << 4], 0u, __ATOMIC_RELAXED,
                           __HIP_MEMORY_SCOPE_AGENT);
        if (tid == 0)
            __hip_atomic_store(&g_c2, 0u, __ATOMIC_RELAXED,
                               __HIP_MEMORY_SCOPE_AGENT);
    }
    if (tid >= 64) return;   // one wave finishes the job

    const unsigned long long v =
        __hip_atomic_load(&g2_ab[tid << 3], __ATOMIC_RELAXED, __HIP_MEMORY_SCOPE_AGENT);
    const unsigned mm =
        __hip_atomic_load(&g2_m[tid << 4], __ATOMIC_RELAXED, __HIP_MEMORY_SCOPE_AGENT);
    float A = __uint_as_float((unsigned)(v & 0xffffffffull));
    float C = __uint_as_float((unsigned)(v >> 32));
    float M = __uint_as_float(mm);
    #pragma unroll
    for (int off = 32; off > 0; off >>= 1) {
        A += __shfl_down(A, off); C += __shfl_down(C, off); M += __shfl_down(M, off);
    }
    if (tid == 0) {
        // loss = ( masked_gt2pred/(mask_sum+1) + pred2gt_sum/(B*N*2) ) / 2
        out[0] = (C / (M + 1.0f) + A * (1.0f / 262144.0f)) * 0.5f;
    }
}

extern "C" void kernel_launch(void* const* d_in, const int* in_sizes, int n_in,
                              void* d_out, int out_size, void* d_ws, size_t ws_size,
                              hipStream_t stream)
{
    const float2* ini  = (const float2*)d_in[0];
    const float2* pred = (const float2*)d_in[1];
    const float2* gt   = (const float2*)d_in[2];
    const float*  kpm  = (const float*)d_in[3];
    float* out = (float*)d_out;
    // d_ws intentionally unused; single fused launch.

    dm_main<<<Bn, 256, 0, stream>>>(ini, pred, gt, kpm, out);
}